// Round 6
// baseline (144.582 us; speedup 1.0000x reference)
//
#include <hip/hip_runtime.h>
#include <hip/hip_bf16.h>
#include <stdint.h>

#define B_ 64
#define S_ 512
#define I_ 256
#define H_ 1024
#define O_ 128
#define M_ (B_*S_)   // 32768

typedef float f32x4 __attribute__((ext_vector_type(4)));
typedef unsigned short u16x4 __attribute__((ext_vector_type(4)));
typedef unsigned short u16x8 __attribute__((ext_vector_type(8)));

__device__ __forceinline__ unsigned short f2bf(float f) {
    unsigned u = __float_as_uint(f);
    u += 0x7FFFu + ((u >> 16) & 1u);
    return (unsigned short)(u >> 16);
}
__device__ __forceinline__ float bf2f(unsigned short s) {
    return __uint_as_float((unsigned)s << 16);
}

// ---- K0: fp32 -> fp8 e4m3 into per-lane fragment order, via LDS transpose.
// A region: [tile128][kq(8)][rb(8)][lane*8B]; B: [hn(16)][kq(8)][rb(4)][lane*8B].
// Fragment: lane l holds row rb*16+(l&15), k = kq*32+(l>>4)*8..+8.
// 32 source rows per block (1056 blocks) for latency hiding; reads and writes
// both coalesced, LDS (stride-65 u32) decouples the orders.
__global__ void __launch_bounds__(256) k0_convert(
    const float* __restrict__ x, const float* __restrict__ Win,
    uint8_t* __restrict__ xf8, uint8_t* __restrict__ wf8,
    unsigned* __restrict__ firstCross)
{
    __shared__ unsigned lds32[32 * 65];   // 8.3 KB
    const int i = blockIdx.x;             // 0..1023 x-blocks, 1024..1055 W-blocks
    const int t = threadIdx.x;

    const float* src;
    uint8_t* dstBase;   // already offset to this block's rb pair
    int kqStride;
    if (i < 1024) {
        src = x + (size_t)(i * 32) * 256;
        dstBase = xf8 + (size_t)(i >> 2) * 32768 + (i & 3) * 2 * 512;
        kqStride = 4096;
    } else {
        const int i2 = i - 1024;
        src = Win + (size_t)(i2 * 32) * 256;
        dstBase = wf8 + (size_t)(i2 >> 1) * 16384 + (i2 & 1) * 2 * 512;
        kqStride = 2048;
    }

    // read: 32 rows x 64 float4; wave reads one full 1KB row per inst
#pragma unroll
    for (int j = 0; j < 8; ++j) {
        const int f = j * 256 + t;
        const int lrow = f >> 6, c4 = f & 63;
        float4 v = *(const float4*)(src + (size_t)lrow * 256 + c4 * 4);
        int w0 = 0;
        w0 = __builtin_amdgcn_cvt_pk_fp8_f32(v.x, v.y, w0, false);
        w0 = __builtin_amdgcn_cvt_pk_fp8_f32(v.z, v.w, w0, true);
        lds32[lrow * 65 + c4] = (unsigned)w0;
    }
    __syncthreads();

    // write: 512 x 16B chunks in fragment order, contiguous per wave
#pragma unroll
    for (int j = 0; j < 2; ++j) {
        const int c = j * 256 + t;
        const int kq  = c >> 6;
        const int rbl = (c >> 5) & 1;
        const int l0  = (c & 31) * 2;
        const int r   = l0 & 15;
        const int q   = l0 >> 4;
        const int lrow = rbl * 16 + r;
        const int c0 = kq * 8 + q * 2;
        uint4 o;
        o.x = lds32[lrow * 65 + c0];
        o.y = lds32[lrow * 65 + c0 + 1];
        o.z = lds32[(lrow + 1) * 65 + c0];
        o.w = lds32[(lrow + 1) * 65 + c0 + 1];
        *(uint4*)(dstBase + kq * kqStride + rbl * 512 + l0 * 8) = o;
    }

    if (i == 0 && t < 64) firstCross[t] = 0xFFFFFFFFu;
}

// ---- KF: fp8 GEMM + lag-one scan, wave-specialized -----------------------
// 1024 blocks = (b 64) x (hn 16). 320 threads = 4 GEMM waves + 1 scan wave.
// B frags in LDS (staged once); A frags hoisted (16 loads -> one wait);
// lS double-buffered so the scan of tile tt-1 overlaps GEMM of tile tt.
__global__ void __launch_bounds__(320) kf_gemm_scan(
    const uint8_t* __restrict__ xf8, const uint8_t* __restrict__ wf8,
    const float* __restrict__ b_in, const float* __restrict__ b_rec,
    const float* __restrict__ tau_m, const float* __restrict__ tau_n,
    unsigned* __restrict__ firstCross)
{
    __shared__ uint8_t lB[16384];        // B fragment slice (linear copy)
    __shared__ uint8_t lS[2][16384];     // [granule16][h64][8t] bf16, x2

    const int tid  = threadIdx.x;
    const int w    = tid >> 6;           // 0..3 GEMM, 4 scan
    const int lane = tid & 63;
    const int idx  = blockIdx.x;
    const int b    = (idx & 7) | ((idx >> 7) << 3);   // XCD swizzle
    const int hn   = (idx >> 3) & 15;
    const int colrow = lane & 15;
    const int quad   = lane >> 4;

    // stage B slice (16 KB) via async DMA: waves 0..3, 4 KB each
    if (w < 4) {
        const uint8_t* gB = wf8 + (size_t)hn * 16384;
#pragma unroll
        for (int j = 0; j < 4; ++j) {
            const int off = (w * 4 + j) * 1024 + lane * 16;
            __builtin_amdgcn_global_load_lds(
                (const __attribute__((address_space(1))) void*)(gB + off),
                (__attribute__((address_space(3))) void*)(lB + off), 16, 0, 0);
        }
    }

    // scan state (wave 4, one h column per lane)
    float alpha = 0.f, beta = 0.f, cbr = 0.f, oma = 0.f, ombr = 0.f;
    float d = 0.f, mem = 0.f;
    unsigned cross = 0xFFFFFFFFu;
    if (w == 4) {
        const int hs = hn * 64 + lane;
        alpha = 1.f / (1.f + expf(-tau_m[hs]));
        beta  = 1.f / (1.f + expf(-tau_n[hs]));
        oma = 1.f - alpha; ombr = 1.f - beta;
        cbr = ombr * (b_in[hs] + b_rec[hs]);
    }
    __syncthreads();   // lB staged

    for (int tt = 0; tt < 4; ++tt) {
        if (w < 4) {
            // ---- GEMM waves: tile tt, t-band w*32..+31 ----
            const uint8_t* xA = xf8 + (size_t)(b * 4 + tt) * 32768
                              + w * 1024 + lane * 8;
            long long a[16];
#pragma unroll
            for (int kq = 0; kq < 8; ++kq) {   // all A loads in flight at once
                a[kq * 2]     = *(const long long*)(xA + kq * 4096);
                a[kq * 2 + 1] = *(const long long*)(xA + kq * 4096 + 512);
            }
            f32x4 acc[2][4];
#pragma unroll
            for (int mi = 0; mi < 2; ++mi)
#pragma unroll
                for (int ni = 0; ni < 4; ++ni)
                    acc[mi][ni] = (f32x4){0.f, 0.f, 0.f, 0.f};
#pragma unroll
            for (int kq = 0; kq < 8; ++kq) {
                long long bfr[4];
#pragma unroll
                for (int ni = 0; ni < 4; ++ni)
                    bfr[ni] = *(const long long*)(lB + kq * 2048 + ni * 512 + lane * 8);
#pragma unroll
                for (int mi = 0; mi < 2; ++mi)
#pragma unroll
                    for (int ni = 0; ni < 4; ++ni)
                        acc[mi][ni] = __builtin_amdgcn_mfma_f32_16x16x32_fp8_fp8(
                            a[kq * 2 + mi], bfr[ni], acc[mi][ni], 0, 0, 0);
            }
            // dump tile tt -> lS[tt&1]
            uint8_t* buf = lS[tt & 1];
#pragma unroll
            for (int mi = 0; mi < 2; ++mi) {
                const int t0 = w * 32 + mi * 16 + quad * 4;
                const int gb = (t0 >> 3) * 1024 + (t0 & 7) * 2;
#pragma unroll
                for (int ni = 0; ni < 4; ++ni) {
                    const int h0 = ni * 16 + colrow;
                    u16x4 p;
                    p[0] = f2bf(acc[mi][ni][0]);
                    p[1] = f2bf(acc[mi][ni][1]);
                    p[2] = f2bf(acc[mi][ni][2]);
                    p[3] = f2bf(acc[mi][ni][3]);
                    *(u16x4*)(buf + gb + h0 * 16) = p;
                }
            }
        } else if (tt > 0) {
            // ---- scan wave: tile tt-1 from the other buffer ----
            const uint8_t* rowp = lS[(tt - 1) & 1] + lane * 16;
            for (int tl0 = 0; tl0 < 128; tl0 += 16) {
                const int gb = (tl0 >> 3) * 1024;
                u16x8 v0 = *(const u16x8*)(rowp + gb);
                u16x8 v1 = *(const u16x8*)(rowp + gb + 1024);
                float f[16];
#pragma unroll
                for (int u = 0; u < 8; ++u) { f[u] = bf2f(v0[u]); f[8 + u] = bf2f(v1[u]); }
#pragma unroll
                for (int u = 0; u < 16; ++u) {
                    d   = fmaf(beta,  d,   fmaf(ombr, f[u], cbr));
                    mem = fmaf(alpha, mem, oma * d);
                    if (mem > 1.0f) {
                        unsigned ts = (unsigned)((tt - 1) * 128 + tl0 + u);
                        if (ts < cross) cross = ts;
                    }
                }
            }
        }
        __syncthreads();
    }

    if (w == 4) {   // final tile (3) after last barrier; GEMM waves may exit
        const uint8_t* rowp = lS[1] + lane * 16;
        for (int tl0 = 0; tl0 < 128; tl0 += 16) {
            const int gb = (tl0 >> 3) * 1024;
            u16x8 v0 = *(const u16x8*)(rowp + gb);
            u16x8 v1 = *(const u16x8*)(rowp + gb + 1024);
            float f[16];
#pragma unroll
            for (int u = 0; u < 8; ++u) { f[u] = bf2f(v0[u]); f[8 + u] = bf2f(v1[u]); }
#pragma unroll
            for (int u = 0; u < 16; ++u) {
                d   = fmaf(beta,  d,   fmaf(ombr, f[u], cbr));
                mem = fmaf(alpha, mem, oma * d);
                if (mem > 1.0f) {
                    unsigned ts = (unsigned)(3 * 128 + tl0 + u);
                    if (ts < cross) cross = ts;
                }
            }
        }
        if (cross != 0xFFFFFFFFu) atomicMin(firstCross + b, cross);
    }
}

// ---- K3: exact repair + output for spiking batches (runs ~never) ----------
__global__ void __launch_bounds__(1024) k3_repair(
    const float* __restrict__ x, const float* __restrict__ W_in,
    const float* __restrict__ b_in,
    const float* __restrict__ W_rec, const float* __restrict__ b_rec,
    const float* __restrict__ tau_m, const float* __restrict__ tau_n,
    const float* __restrict__ W_out, const float* __restrict__ b_out,
    const unsigned* __restrict__ firstCross,
    unsigned long long* __restrict__ gmask,
    float* __restrict__ out)
{
    const int b = blockIdx.x;
    if (firstCross[b] == 0xFFFFFFFFu) return;   // block-uniform
    const int h = threadIdx.x;
    __shared__ float xrow[I_];
    __shared__ unsigned long long msk[16];
    if (h < 16) msk[h] = 0ull;
    const float alpha = 1.f / (1.f + expf(-tau_m[h]));
    const float beta  = 1.f / (1.f + expf(-tau_n[h]));
    const float bsum  = b_in[h] + b_rec[h];
    const float* wi = W_in + (size_t)h * I_;
    const float* wr = W_rec + (size_t)h * H_;
    float d = 0.f, mem = 0.f;
    for (int t = 0; t < S_; ++t) {
        __syncthreads();
        if (h < I_) xrow[h] = x[((size_t)b * S_ + t) * I_ + h];
        __syncthreads();
        float ffv = 0.f;
        for (int k = 0; k < I_; ++k) ffv += xrow[k] * wi[k];
        float rec = 0.f;
#pragma unroll
        for (int wd = 0; wd < 16; ++wd) {
            unsigned long long mw = msk[wd];
            while (mw) {
                int bit = __ffsll((long long)mw) - 1;
                rec += wr[(wd << 6) + bit];
                mw &= (mw - 1);
            }
        }
        float tot = ffv + bsum + rec;
        d   = beta  * d   + (1.f - beta)  * tot;
        mem = alpha * mem + (1.f - alpha) * d;
        int sp = (mem > 1.0f) ? 1 : 0;
        if (sp) mem = 0.f;
        unsigned long long bal = __ballot(sp);
        __syncthreads();
        if ((h & 63) == 0) {
            msk[h >> 6] = bal;
            gmask[((size_t)b * S_ + t) * 16 + (h >> 6)] = bal;
        }
    }
    __syncthreads();
    __threadfence_block();
    for (int i = h; i < S_ * O_; i += 1024) {
        const int t = i >> 7, o = i & (O_ - 1);
        float logit = b_out[o];
        const unsigned long long* m = gmask + ((size_t)b * S_ + t) * 16;
        const float* wo = W_out + (size_t)o * H_;
        for (int wd = 0; wd < 16; ++wd) {
            unsigned long long mw = m[wd];
            while (mw) {
                int bit = __ffsll((long long)mw) - 1;
                logit += wo[(wd << 6) + bit];
                mw &= (mw - 1);
            }
        }
        out[((size_t)b * S_ + t) * O_ + o] = 1.f / (1.f + expf(-logit));
    }
}

// ---- K4: fast-path output for non-spiking batches -------------------------
__global__ void __launch_bounds__(256) k4_out(
    const float* __restrict__ b_out,
    const unsigned* __restrict__ firstCross,
    float* __restrict__ out)
{
    const int i4 = blockIdx.x * 256 + threadIdx.x;   // float4 index
    const int b  = i4 >> 14;                         // 16384 float4 per batch
    if (firstCross[b] != 0xFFFFFFFFu) return;        // k3 owns this batch
    const int o4 = i4 & 31;
    float4 v = *(const float4*)(b_out + o4 * 4);
    float4 r;
    r.x = 1.f / (1.f + expf(-v.x));
    r.y = 1.f / (1.f + expf(-v.y));
    r.z = 1.f / (1.f + expf(-v.z));
    r.w = 1.f / (1.f + expf(-v.w));
    *(float4*)(out + (size_t)i4 * 4) = r;
}

extern "C" void kernel_launch(void* const* d_in, const int* in_sizes, int n_in,
                              void* d_out, int out_size, void* d_ws, size_t ws_size,
                              hipStream_t stream) {
    const float* x     = (const float*)d_in[0];
    const float* W_in  = (const float*)d_in[1];
    const float* b_in  = (const float*)d_in[2];
    const float* W_rec = (const float*)d_in[3];
    const float* b_rec = (const float*)d_in[4];
    const float* tau_m = (const float*)d_in[5];
    const float* tau_n = (const float*)d_in[6];
    const float* W_out = (const float*)d_in[7];
    const float* b_out = (const float*)d_in[8];
    float* out = (float*)d_out;

    char* ws = (char*)d_ws;
    size_t off = 0;
    uint8_t* xf8 = (uint8_t*)(ws + off);               off += (size_t)M_ * I_;        // 8 MB
    uint8_t* wf8 = (uint8_t*)(ws + off);               off += (size_t)H_ * I_;        // 256 KB
    unsigned long long* gmask = (unsigned long long*)(ws + off); off += (size_t)B_ * S_ * 16 * 8; // 4 MB
    unsigned* firstCross = (unsigned*)(ws + off);      off += 256;
    if (ws_size < off) return;

    k0_convert<<<1056, 256, 0, stream>>>(x, W_in, xf8, wf8, firstCross);
    kf_gemm_scan<<<1024, 320, 0, stream>>>(xf8, wf8, b_in, b_rec, tau_m, tau_n,
                                           firstCross);
    k3_repair<<<64, 1024, 0, stream>>>(x, W_in, b_in, W_rec, b_rec, tau_m, tau_n,
                                       W_out, b_out, firstCross, gmask, out);
    k4_out<<<4096, 256, 0, stream>>>(b_out, firstCross, out);
}